// Round 2
// baseline (917.466 us; speedup 1.0000x reference)
//
#include <hip/hip_runtime.h>
#include <hip/hip_bf16.h>

// Problem constants (match reference)
#define NN   8192      // nodes
#define NE   524288    // edges
#define DH   16384     // 2N hidden
#define NOUT 32

// ---------------------------------------------------------------------------
// GCN stage kernels (unchanged from R1 — atomics not indicted yet)
// ---------------------------------------------------------------------------

__global__ __launch_bounds__(256) void k_deg_init(float* deg) {
    int i = blockIdx.x * blockDim.x + threadIdx.x;
    if (i < NN) deg[i] = 1.0f;   // self-loop contributes 1
}

__global__ __launch_bounds__(256) void k_deg_acc(const int* __restrict__ dst, float* deg) {
    int e = blockIdx.x * blockDim.x + threadIdx.x;
    if (e < NE) atomicAdd(&deg[dst[e]], 1.0f);
}

// dinv = rsqrt(deg) (in place); h1 = x0 @ W1.T ; zero agg1
__global__ __launch_bounds__(256) void k_dinv_h1(const float* __restrict__ x0,
                                                 const float* __restrict__ W1,
                                                 float* dinv, float* h1, float* agg1) {
    int i = blockIdx.x * blockDim.x + threadIdx.x;
    if (i >= NN) return;
    dinv[i] = rsqrtf(dinv[i]);           // deg >= 1 always (self-loop)
    float a = x0[2 * i], b = x0[2 * i + 1];
#pragma unroll
    for (int c = 0; c < 4; ++c) {
        h1[4 * i + c] = a * W1[2 * c] + b * W1[2 * c + 1];
        agg1[4 * i + c] = 0.0f;
    }
}

__global__ __launch_bounds__(256) void k_scat4(const int* __restrict__ src,
                                               const int* __restrict__ dst,
                                               const float* __restrict__ dinv,
                                               const float* __restrict__ h,
                                               float* agg) {
    int e = blockIdx.x * blockDim.x + threadIdx.x;
    if (e >= NE) return;
    int s = src[e], d = dst[e];
    float nrm = dinv[s] * dinv[d];
    float4 hv = *(const float4*)(h + 4 * s);
    atomicAdd(&agg[4 * d + 0], nrm * hv.x);
    atomicAdd(&agg[4 * d + 1], nrm * hv.y);
    atomicAdd(&agg[4 * d + 2], nrm * hv.z);
    atomicAdd(&agg[4 * d + 3], nrm * hv.w);
}

// x1 = relu(agg1 + dinv^2*h1 + b1); h2 = x1 @ W2.T ; zero agg2   (x1 never stored)
__global__ __launch_bounds__(256) void k_fin1_h2(const float* __restrict__ dinv,
                                                 const float* __restrict__ h1,
                                                 const float* __restrict__ agg1,
                                                 const float* __restrict__ b1,
                                                 const float* __restrict__ W2,
                                                 float* h2, float* agg2) {
    int i = blockIdx.x * blockDim.x + threadIdx.x;
    if (i >= NN) return;
    float di2 = dinv[i] * dinv[i];
    float x1[4];
#pragma unroll
    for (int c = 0; c < 4; ++c) {
        float t = agg1[4 * i + c] + di2 * h1[4 * i + c] + b1[c];
        x1[c] = fmaxf(t, 0.0f);
    }
#pragma unroll
    for (int c = 0; c < 2; ++c) {
        float t = 0.0f;
#pragma unroll
        for (int k = 0; k < 4; ++k) t += x1[k] * W2[4 * c + k];
        h2[2 * i + c] = t;
        agg2[2 * i + c] = 0.0f;
    }
}

__global__ __launch_bounds__(256) void k_scat2(const int* __restrict__ src,
                                               const int* __restrict__ dst,
                                               const float* __restrict__ dinv,
                                               const float* __restrict__ h,
                                               float* agg) {
    int e = blockIdx.x * blockDim.x + threadIdx.x;
    if (e >= NE) return;
    int s = src[e], d = dst[e];
    float nrm = dinv[s] * dinv[d];
    float2 hv = *(const float2*)(h + 2 * s);
    atomicAdd(&agg[2 * d + 0], nrm * hv.x);
    atomicAdd(&agg[2 * d + 1], nrm * hv.y);
}

// x2 = relu(agg2 + dinv^2*h2 + b2); h3 = x2 @ W3.T ; zero agg3
__global__ __launch_bounds__(256) void k_fin2_h3(const float* __restrict__ dinv,
                                                 const float* __restrict__ h2,
                                                 const float* __restrict__ agg2,
                                                 const float* __restrict__ b2,
                                                 const float* __restrict__ W3,
                                                 float* h3, float* agg3) {
    int i = blockIdx.x * blockDim.x + threadIdx.x;
    if (i >= NN) return;
    float di2 = dinv[i] * dinv[i];
    float x2a = fmaxf(agg2[2 * i + 0] + di2 * h2[2 * i + 0] + b2[0], 0.0f);
    float x2b = fmaxf(agg2[2 * i + 1] + di2 * h2[2 * i + 1] + b2[1], 0.0f);
    h3[i] = x2a * W3[0] + x2b * W3[1];
    agg3[i] = 0.0f;
}

__global__ __launch_bounds__(256) void k_scat1(const int* __restrict__ src,
                                               const int* __restrict__ dst,
                                               const float* __restrict__ dinv,
                                               const float* __restrict__ h,
                                               float* agg) {
    int e = blockIdx.x * blockDim.x + threadIdx.x;
    if (e >= NE) return;
    int s = src[e], d = dst[e];
    atomicAdd(&agg[d], dinv[s] * dinv[d] * h[s]);
}

__global__ __launch_bounds__(256) void k_fin3(const float* __restrict__ dinv,
                                              const float* __restrict__ h3,
                                              const float* __restrict__ agg3,
                                              const float* __restrict__ b3,
                                              float* v) {
    int i = blockIdx.x * blockDim.x + threadIdx.x;
    if (i >= NN) return;
    v[i] = agg3[i] + dinv[i] * dinv[i] * h3[i] + b3[0];
}

// ---------------------------------------------------------------------------
// Trailing MLP, restructured: ONE WAVE PER ROW.
// No LDS, no __syncthreads — pure shuffle reduce; 4 independent rows/block.
// k_mv1: 16384 rows -> 4096 blocks; each lane does 32 float4-pair loads.
// ---------------------------------------------------------------------------

__global__ __launch_bounds__(256) void k_mv1(const float* __restrict__ v,
                                             const float* __restrict__ Wa,
                                             const float* __restrict__ ba,
                                             float* __restrict__ y) {
    int wid  = threadIdx.x >> 6;
    int lane = threadIdx.x & 63;
    int j = blockIdx.x * 4 + wid;                 // row of Wa
    const float4* wr = (const float4*)(Wa + (size_t)j * NN);
    const float4* vv = (const float4*)v;
    float acc = 0.0f;
#pragma unroll 8
    for (int it = 0; it < (NN / 4) / 64; ++it) {  // 32 iters
        int idx = it * 64 + lane;                 // wave reads 1 KB contiguous
        float4 w = wr[idx];
        float4 x = vv[idx];
        acc += w.x * x.x + w.y * x.y + w.z * x.z + w.w * x.w;
    }
#pragma unroll
    for (int off = 32; off > 0; off >>= 1) acc += __shfl_down(acc, off, 64);
    if (lane == 0) y[j] = tanhf(acc + ba[j]);
}

__global__ __launch_bounds__(256) void k_mv2(const float* __restrict__ y,
                                             const float* __restrict__ Wb,
                                             const float* __restrict__ bb,
                                             float* __restrict__ out) {
    int wid  = threadIdx.x >> 6;
    int lane = threadIdx.x & 63;
    int o = blockIdx.x * 4 + wid;                 // row of Wb (32 rows -> 8 blocks)
    const float4* wr = (const float4*)(Wb + (size_t)o * DH);
    const float4* yy = (const float4*)y;
    float acc = 0.0f;
#pragma unroll 8
    for (int it = 0; it < (DH / 4) / 64; ++it) {  // 64 iters
        int idx = it * 64 + lane;
        float4 w = wr[idx];
        float4 x = yy[idx];
        acc += w.x * x.x + w.y * x.y + w.z * x.z + w.w * x.w;
    }
#pragma unroll
    for (int off = 32; off > 0; off >>= 1) acc += __shfl_down(acc, off, 64);
    if (lane == 0) out[o] = tanhf(acc + bb[o]);
}

// ---------------------------------------------------------------------------

extern "C" void kernel_launch(void* const* d_in, const int* in_sizes, int n_in,
                              void* d_out, int out_size, void* d_ws, size_t ws_size,
                              hipStream_t stream) {
    const float* data = (const float*)d_in[0];
    const int*   edge = (const int*)d_in[1];       // [2, E] int32
    const float* W1   = (const float*)d_in[2];
    const float* b1   = (const float*)d_in[3];
    const float* W2   = (const float*)d_in[4];
    const float* b2   = (const float*)d_in[5];
    const float* W3   = (const float*)d_in[6];
    const float* b3   = (const float*)d_in[7];
    const float* Wa   = (const float*)d_in[8];
    const float* ba   = (const float*)d_in[9];
    const float* Wb   = (const float*)d_in[10];
    const float* bb   = (const float*)d_in[11];
    float* out = (float*)d_out;

    const int* src = edge;
    const int* dst = edge + NE;

    // workspace layout (floats) — everything re-initialized each call
    float* ws   = (float*)d_ws;
    float* dinv = ws;                 // [NN]       (deg first, rsqrt in-place)
    float* h1   = dinv + NN;          // [NN*4]
    float* agg1 = h1 + NN * 4;        // [NN*4]
    float* h2   = agg1 + NN * 4;      // [NN*2]
    float* agg2 = h2 + NN * 2;        // [NN*2]
    float* h3   = agg2 + NN * 2;      // [NN]
    float* agg3 = h3 + NN;            // [NN]
    float* v    = agg3 + NN;          // [NN]
    float* y1   = v + NN;             // [DH]

    dim3 blk(256);
    dim3 gN((NN + 255) / 256);        // 32 blocks (node-domain)
    dim3 gE((NE + 255) / 256);        // 2048 blocks (edge-domain)

    k_deg_init<<<gN, blk, 0, stream>>>(dinv);
    k_deg_acc<<<gE, blk, 0, stream>>>(dst, dinv);
    k_dinv_h1<<<gN, blk, 0, stream>>>(data, W1, dinv, h1, agg1);
    k_scat4<<<gE, blk, 0, stream>>>(src, dst, dinv, h1, agg1);
    k_fin1_h2<<<gN, blk, 0, stream>>>(dinv, h1, agg1, b1, W2, h2, agg2);
    k_scat2<<<gE, blk, 0, stream>>>(src, dst, dinv, h2, agg2);
    k_fin2_h3<<<gN, blk, 0, stream>>>(dinv, h2, agg2, b2, W3, h3, agg3);
    k_scat1<<<gE, blk, 0, stream>>>(src, dst, dinv, h3, agg3);
    k_fin3<<<gN, blk, 0, stream>>>(dinv, h3, agg3, b3, v);
    k_mv1<<<dim3(DH / 4), blk, 0, stream>>>(v, Wa, ba, y1);
    k_mv2<<<dim3(NOUT / 4), blk, 0, stream>>>(y1, Wb, bb, out);
}

// Round 3
// 894.287 us; speedup vs baseline: 1.0259x; 1.0259x over previous
//
#include <hip/hip_runtime.h>
#include <hip/hip_bf16.h>

// Problem constants (match reference)
#define NN   8192      // nodes
#define NE   524288    // edges
#define DH   16384     // 2N hidden
#define NOUT 32

typedef float f32x4 __attribute__((ext_vector_type(4)));

// ---------------------------------------------------------------------------
// GCN stage kernels
// degacc buffer is pre-zeroed by hipMemsetAsync; self-loop +1 folded into rsqrt.
// ---------------------------------------------------------------------------

__global__ __launch_bounds__(256) void k_deg_acc(const int* __restrict__ dst, float* degacc) {
    int e = blockIdx.x * blockDim.x + threadIdx.x;
    if (e < NE) atomicAdd(&degacc[dst[e]], 1.0f);
}

// dinv = rsqrt(1 + degacc) (in place); h1 = x0 @ W1.T
__global__ __launch_bounds__(256) void k_dinv_h1(const float* __restrict__ x0,
                                                 const float* __restrict__ W1,
                                                 float* dinv, float* h1) {
    int i = blockIdx.x * blockDim.x + threadIdx.x;
    if (i >= NN) return;
    dinv[i] = rsqrtf(dinv[i] + 1.0f);    // deg = 1 (self-loop) + incoming count
    float a = x0[2 * i], b = x0[2 * i + 1];
    f32x4 h;
#pragma unroll
    for (int c = 0; c < 4; ++c) h[c] = a * W1[2 * c] + b * W1[2 * c + 1];
    *(f32x4*)(h1 + 4 * i) = h;
}

__global__ __launch_bounds__(256) void k_scat4(const int* __restrict__ src,
                                               const int* __restrict__ dst,
                                               const float* __restrict__ dinv,
                                               const float* __restrict__ h,
                                               float* agg) {
    int e = blockIdx.x * blockDim.x + threadIdx.x;
    if (e >= NE) return;
    int s = src[e], d = dst[e];
    float nrm = dinv[s] * dinv[d];
    float4 hv = *(const float4*)(h + 4 * s);
    atomicAdd(&agg[4 * d + 0], nrm * hv.x);
    atomicAdd(&agg[4 * d + 1], nrm * hv.y);
    atomicAdd(&agg[4 * d + 2], nrm * hv.z);
    atomicAdd(&agg[4 * d + 3], nrm * hv.w);
}

// x1 = relu(agg1 + dinv^2*h1 + b1); h2 = x1 @ W2.T    (x1 never stored)
__global__ __launch_bounds__(256) void k_fin1_h2(const float* __restrict__ dinv,
                                                 const float* __restrict__ h1,
                                                 const float* __restrict__ agg1,
                                                 const float* __restrict__ b1,
                                                 const float* __restrict__ W2,
                                                 float* h2) {
    int i = blockIdx.x * blockDim.x + threadIdx.x;
    if (i >= NN) return;
    float di2 = dinv[i] * dinv[i];
    float x1[4];
#pragma unroll
    for (int c = 0; c < 4; ++c) {
        float t = agg1[4 * i + c] + di2 * h1[4 * i + c] + b1[c];
        x1[c] = fmaxf(t, 0.0f);
    }
#pragma unroll
    for (int c = 0; c < 2; ++c) {
        float t = 0.0f;
#pragma unroll
        for (int k = 0; k < 4; ++k) t += x1[k] * W2[4 * c + k];
        h2[2 * i + c] = t;
    }
}

__global__ __launch_bounds__(256) void k_scat2(const int* __restrict__ src,
                                               const int* __restrict__ dst,
                                               const float* __restrict__ dinv,
                                               const float* __restrict__ h,
                                               float* agg) {
    int e = blockIdx.x * blockDim.x + threadIdx.x;
    if (e >= NE) return;
    int s = src[e], d = dst[e];
    float nrm = dinv[s] * dinv[d];
    float2 hv = *(const float2*)(h + 2 * s);
    atomicAdd(&agg[2 * d + 0], nrm * hv.x);
    atomicAdd(&agg[2 * d + 1], nrm * hv.y);
}

// x2 = relu(agg2 + dinv^2*h2 + b2); h3 = x2 @ W3.T
__global__ __launch_bounds__(256) void k_fin2_h3(const float* __restrict__ dinv,
                                                 const float* __restrict__ h2,
                                                 const float* __restrict__ agg2,
                                                 const float* __restrict__ b2,
                                                 const float* __restrict__ W3,
                                                 float* h3) {
    int i = blockIdx.x * blockDim.x + threadIdx.x;
    if (i >= NN) return;
    float di2 = dinv[i] * dinv[i];
    float x2a = fmaxf(agg2[2 * i + 0] + di2 * h2[2 * i + 0] + b2[0], 0.0f);
    float x2b = fmaxf(agg2[2 * i + 1] + di2 * h2[2 * i + 1] + b2[1], 0.0f);
    h3[i] = x2a * W3[0] + x2b * W3[1];
}

__global__ __launch_bounds__(256) void k_scat1(const int* __restrict__ src,
                                               const int* __restrict__ dst,
                                               const float* __restrict__ dinv,
                                               const float* __restrict__ h,
                                               float* agg) {
    int e = blockIdx.x * blockDim.x + threadIdx.x;
    if (e >= NE) return;
    int s = src[e], d = dst[e];
    atomicAdd(&agg[d], dinv[s] * dinv[d] * h[s]);
}

__global__ __launch_bounds__(256) void k_fin3(const float* __restrict__ dinv,
                                              const float* __restrict__ h3,
                                              const float* __restrict__ agg3,
                                              const float* __restrict__ b3,
                                              float* v) {
    int i = blockIdx.x * blockDim.x + threadIdx.x;
    if (i >= NN) return;
    v[i] = agg3[i] + dinv[i] * dinv[i] * h3[i] + b3[0];
}

// ---------------------------------------------------------------------------
// Trailing MLP: one wave per row, shuffle reduce, non-temporal weight stream.
// ---------------------------------------------------------------------------

__global__ __launch_bounds__(256) void k_mv1(const float* __restrict__ v,
                                             const float* __restrict__ Wa,
                                             const float* __restrict__ ba,
                                             float* __restrict__ y) {
    int wid  = threadIdx.x >> 6;
    int lane = threadIdx.x & 63;
    int j = blockIdx.x * 4 + wid;                 // row of Wa
    const f32x4* wr = (const f32x4*)(Wa + (size_t)j * NN);
    const f32x4* vv = (const f32x4*)v;
    float acc = 0.0f;
#pragma unroll 8
    for (int it = 0; it < (NN / 4) / 64; ++it) {  // 32 iters
        int idx = it * 64 + lane;                 // wave reads 1 KB contiguous
        f32x4 w = __builtin_nontemporal_load(&wr[idx]);   // Wa streamed once, 2x LLC
        f32x4 x = vv[idx];
        acc += w.x * x.x + w.y * x.y + w.z * x.z + w.w * x.w;
    }
#pragma unroll
    for (int off = 32; off > 0; off >>= 1) acc += __shfl_down(acc, off, 64);
    if (lane == 0) y[j] = tanhf(acc + ba[j]);
}

__global__ __launch_bounds__(256) void k_mv2(const float* __restrict__ y,
                                             const float* __restrict__ Wb,
                                             const float* __restrict__ bb,
                                             float* __restrict__ out) {
    int wid  = threadIdx.x >> 6;
    int lane = threadIdx.x & 63;
    int o = blockIdx.x * 4 + wid;                 // row of Wb (32 rows -> 8 blocks)
    const f32x4* wr = (const f32x4*)(Wb + (size_t)o * DH);
    const f32x4* yy = (const f32x4*)y;
    float acc = 0.0f;
#pragma unroll 8
    for (int it = 0; it < (DH / 4) / 64; ++it) {  // 64 iters
        int idx = it * 64 + lane;
        f32x4 w = wr[idx];
        f32x4 x = yy[idx];
        acc += w.x * x.x + w.y * x.y + w.z * x.z + w.w * x.w;
    }
#pragma unroll
    for (int off = 32; off > 0; off >>= 1) acc += __shfl_down(acc, off, 64);
    if (lane == 0) out[o] = tanhf(acc + bb[o]);
}

// ---------------------------------------------------------------------------

extern "C" void kernel_launch(void* const* d_in, const int* in_sizes, int n_in,
                              void* d_out, int out_size, void* d_ws, size_t ws_size,
                              hipStream_t stream) {
    const float* data = (const float*)d_in[0];
    const int*   edge = (const int*)d_in[1];       // [2, E] int32
    const float* W1   = (const float*)d_in[2];
    const float* b1   = (const float*)d_in[3];
    const float* W2   = (const float*)d_in[4];
    const float* b2   = (const float*)d_in[5];
    const float* W3   = (const float*)d_in[6];
    const float* b3   = (const float*)d_in[7];
    const float* Wa   = (const float*)d_in[8];
    const float* ba   = (const float*)d_in[9];
    const float* Wb   = (const float*)d_in[10];
    const float* bb   = (const float*)d_in[11];
    float* out = (float*)d_out;

    const int* src = edge;
    const int* dst = edge + NE;

    // workspace layout (floats) — zero-init region is contiguous at the front
    float* ws   = (float*)d_ws;
    float* dinv = ws;                 // [NN]    degacc (memset 0) -> rsqrt in place
    float* agg1 = dinv + NN;          // [NN*4]  memset 0
    float* agg2 = agg1 + NN * 4;      // [NN*2]  memset 0
    float* agg3 = agg2 + NN * 2;      // [NN]    memset 0
    float* h1   = agg3 + NN;          // [NN*4]
    float* h2   = h1 + NN * 4;        // [NN*2]
    float* h3   = h2 + NN * 2;        // [NN]
    float* v    = h3 + NN;            // [NN]
    float* y1   = v + NN;             // [DH]

    dim3 blk(256);
    dim3 gN((NN + 255) / 256);        // 32 blocks (node-domain)
    dim3 gE((NE + 255) / 256);        // 2048 blocks (edge-domain)

    // one memset zeroes degacc + agg1 + agg2 + agg3 (8*NN floats = 256 KB)
    hipMemsetAsync(dinv, 0, (size_t)(NN * 8) * sizeof(float), stream);

    k_deg_acc<<<gE, blk, 0, stream>>>(dst, dinv);
    k_dinv_h1<<<gN, blk, 0, stream>>>(data, W1, dinv, h1);
    k_scat4<<<gE, blk, 0, stream>>>(src, dst, dinv, h1, agg1);
    k_fin1_h2<<<gN, blk, 0, stream>>>(dinv, h1, agg1, b1, W2, h2);
    k_scat2<<<gE, blk, 0, stream>>>(src, dst, dinv, h2, agg2);
    k_fin2_h3<<<gN, blk, 0, stream>>>(dinv, h2, agg2, b2, W3, h3);
    k_scat1<<<gE, blk, 0, stream>>>(src, dst, dinv, h3, agg3);
    k_fin3<<<gN, blk, 0, stream>>>(dinv, h3, agg3, b3, v);
    k_mv1<<<dim3(DH / 4), blk, 0, stream>>>(v, Wa, ba, y1);
    k_mv2<<<dim3(NOUT / 4), blk, 0, stream>>>(y1, Wb, bb, out);
}

// Round 4
// 747.615 us; speedup vs baseline: 1.2272x; 1.1962x over previous
//
#include <hip/hip_runtime.h>
#include <hip/hip_bf16.h>

// Problem constants (match reference)
#define NN   8192      // nodes
#define NE   524288    // edges
#define DH   16384     // 2N hidden
#define NOUT 32

typedef float f32x4 __attribute__((ext_vector_type(4)));

// ---------------------------------------------------------------------------
// CSR build (counting sort by dst) — int atomics only, 1M total.
// ---------------------------------------------------------------------------

__global__ __launch_bounds__(256) void k_hist(const int* __restrict__ dst, int* cnt) {
    int e = blockIdx.x * blockDim.x + threadIdx.x;
    if (e < NE) atomicAdd(&cnt[dst[e]], 1);
}

// Single block, 256 threads x 32 elements: exclusive scan of cnt -> row/cursor,
// plus dinv = rsqrt(deg) with the self-loop's +1 folded in.
__global__ __launch_bounds__(256) void k_scan(const int* __restrict__ cnt,
                                              int* __restrict__ row,
                                              int* __restrict__ cursor,
                                              float* __restrict__ dinv) {
    __shared__ int sm[256];
    int t = threadIdx.x;
    int base = t * 32;
    int local[32];
    int sum = 0;
#pragma unroll
    for (int k = 0; k < 32; ++k) { local[k] = cnt[base + k]; sum += local[k]; }
    sm[t] = sum;
    __syncthreads();
    for (int off = 1; off < 256; off <<= 1) {
        int v = (t >= off) ? sm[t - off] : 0;
        __syncthreads();
        sm[t] += v;
        __syncthreads();
    }
    int pre = (t == 0) ? 0 : sm[t - 1];
#pragma unroll
    for (int k = 0; k < 32; ++k) {
        row[base + k] = pre;
        cursor[base + k] = pre;
        dinv[base + k] = rsqrtf((float)local[k] + 1.0f);
        pre += local[k];
    }
    if (t == 255) row[NN] = pre;   // == NE
}

__global__ __launch_bounds__(256) void k_build(const int* __restrict__ src,
                                               const int* __restrict__ dst,
                                               int* __restrict__ cursor,
                                               int* __restrict__ srcs) {
    int e = blockIdx.x * blockDim.x + threadIdx.x;
    if (e >= NE) return;
    int p = atomicAdd(&cursor[dst[e]], 1);
    srcs[p] = src[e];
}

// h1 = x0 @ W1.T  (no dinv dependency)
__global__ __launch_bounds__(256) void k_h1(const float* __restrict__ x0,
                                            const float* __restrict__ W1,
                                            float* __restrict__ h1) {
    int i = blockIdx.x * blockDim.x + threadIdx.x;
    if (i >= NN) return;
    float a = x0[2 * i], b = x0[2 * i + 1];
    f32x4 h;
#pragma unroll
    for (int c = 0; c < 4; ++c) h[c] = a * W1[2 * c] + b * W1[2 * c + 1];
    *(f32x4*)(h1 + 4 * i) = h;
}

// ---------------------------------------------------------------------------
// Gather-based aggregation: ONE WAVE PER NODE (4 nodes/block), no atomics.
// out[i] = dinv[i] * (sum_e dinv[s]*h[s] + dinv[i]*h[i]) + bias; then the
// next layer's linear is fused in (x1/x2 never materialized).
// ---------------------------------------------------------------------------

// layer1 agg (C=4) + relu + linear W2 -> h2  [NN*2]
__global__ __launch_bounds__(256) void k_g4(const int* __restrict__ row,
                                            const int* __restrict__ srcs,
                                            const float* __restrict__ dinv,
                                            const float* __restrict__ h1,
                                            const float* __restrict__ b1,
                                            const float* __restrict__ W2,
                                            float* __restrict__ h2) {
    int wid = threadIdx.x >> 6, lane = threadIdx.x & 63;
    int i = blockIdx.x * 4 + wid;
    int beg = row[i], end = row[i + 1];
    float a0 = 0, a1 = 0, a2 = 0, a3 = 0;
    for (int p = beg + lane; p < end; p += 64) {
        int s = srcs[p];
        float w = dinv[s];
        float4 hv = *(const float4*)(h1 + 4 * s);
        a0 += w * hv.x; a1 += w * hv.y; a2 += w * hv.z; a3 += w * hv.w;
    }
#pragma unroll
    for (int off = 32; off > 0; off >>= 1) {
        a0 += __shfl_down(a0, off, 64);
        a1 += __shfl_down(a1, off, 64);
        a2 += __shfl_down(a2, off, 64);
        a3 += __shfl_down(a3, off, 64);
    }
    if (lane == 0) {
        float di = dinv[i];
        float4 hs = *(const float4*)(h1 + 4 * i);
        float x0v = fmaxf(di * (a0 + di * hs.x) + b1[0], 0.0f);
        float x1v = fmaxf(di * (a1 + di * hs.y) + b1[1], 0.0f);
        float x2v = fmaxf(di * (a2 + di * hs.z) + b1[2], 0.0f);
        float x3v = fmaxf(di * (a3 + di * hs.w) + b1[3], 0.0f);
        float2 o;
        o.x = x0v * W2[0] + x1v * W2[1] + x2v * W2[2] + x3v * W2[3];
        o.y = x0v * W2[4] + x1v * W2[5] + x2v * W2[6] + x3v * W2[7];
        *(float2*)(h2 + 2 * i) = o;
    }
}

// layer2 agg (C=2) + relu + linear W3 -> h3  [NN]
__global__ __launch_bounds__(256) void k_g2(const int* __restrict__ row,
                                            const int* __restrict__ srcs,
                                            const float* __restrict__ dinv,
                                            const float* __restrict__ h2,
                                            const float* __restrict__ b2,
                                            const float* __restrict__ W3,
                                            float* __restrict__ h3) {
    int wid = threadIdx.x >> 6, lane = threadIdx.x & 63;
    int i = blockIdx.x * 4 + wid;
    int beg = row[i], end = row[i + 1];
    float a0 = 0, a1 = 0;
    for (int p = beg + lane; p < end; p += 64) {
        int s = srcs[p];
        float w = dinv[s];
        float2 hv = *(const float2*)(h2 + 2 * s);
        a0 += w * hv.x; a1 += w * hv.y;
    }
#pragma unroll
    for (int off = 32; off > 0; off >>= 1) {
        a0 += __shfl_down(a0, off, 64);
        a1 += __shfl_down(a1, off, 64);
    }
    if (lane == 0) {
        float di = dinv[i];
        float2 hs = *(const float2*)(h2 + 2 * i);
        float x0v = fmaxf(di * (a0 + di * hs.x) + b2[0], 0.0f);
        float x1v = fmaxf(di * (a1 + di * hs.y) + b2[1], 0.0f);
        h3[i] = x0v * W3[0] + x1v * W3[1];
    }
}

// layer3 agg (C=1) -> v  [NN]
__global__ __launch_bounds__(256) void k_g1(const int* __restrict__ row,
                                            const int* __restrict__ srcs,
                                            const float* __restrict__ dinv,
                                            const float* __restrict__ h3,
                                            const float* __restrict__ b3,
                                            float* __restrict__ v) {
    int wid = threadIdx.x >> 6, lane = threadIdx.x & 63;
    int i = blockIdx.x * 4 + wid;
    int beg = row[i], end = row[i + 1];
    float a0 = 0;
    for (int p = beg + lane; p < end; p += 64) {
        int s = srcs[p];
        a0 += dinv[s] * h3[s];
    }
#pragma unroll
    for (int off = 32; off > 0; off >>= 1) a0 += __shfl_down(a0, off, 64);
    if (lane == 0) {
        float di = dinv[i];
        v[i] = di * (a0 + di * h3[i]) + b3[0];
    }
}

// ---------------------------------------------------------------------------
// Trailing MLP: one wave per row, shuffle reduce, non-temporal weight stream.
// ---------------------------------------------------------------------------

__global__ __launch_bounds__(256) void k_mv1(const float* __restrict__ v,
                                             const float* __restrict__ Wa,
                                             const float* __restrict__ ba,
                                             float* __restrict__ y) {
    int wid  = threadIdx.x >> 6;
    int lane = threadIdx.x & 63;
    int j = blockIdx.x * 4 + wid;                 // row of Wa
    const f32x4* wr = (const f32x4*)(Wa + (size_t)j * NN);
    const f32x4* vv = (const f32x4*)v;
    float acc = 0.0f;
#pragma unroll 8
    for (int it = 0; it < (NN / 4) / 64; ++it) {  // 32 iters
        int idx = it * 64 + lane;                 // wave reads 1 KB contiguous
        f32x4 w = __builtin_nontemporal_load(&wr[idx]);   // Wa streamed once, 2x LLC
        f32x4 x = vv[idx];
        acc += w.x * x.x + w.y * x.y + w.z * x.z + w.w * x.w;
    }
#pragma unroll
    for (int off = 32; off > 0; off >>= 1) acc += __shfl_down(acc, off, 64);
    if (lane == 0) y[j] = tanhf(acc + ba[j]);
}

__global__ __launch_bounds__(256) void k_mv2(const float* __restrict__ y,
                                             const float* __restrict__ Wb,
                                             const float* __restrict__ bb,
                                             float* __restrict__ out) {
    int wid  = threadIdx.x >> 6;
    int lane = threadIdx.x & 63;
    int o = blockIdx.x * 4 + wid;                 // row of Wb (32 rows -> 8 blocks)
    const f32x4* wr = (const f32x4*)(Wb + (size_t)o * DH);
    const f32x4* yy = (const f32x4*)y;
    float acc = 0.0f;
#pragma unroll 8
    for (int it = 0; it < (DH / 4) / 64; ++it) {  // 64 iters
        int idx = it * 64 + lane;
        f32x4 w = wr[idx];
        f32x4 x = yy[idx];
        acc += w.x * x.x + w.y * x.y + w.z * x.z + w.w * x.w;
    }
#pragma unroll
    for (int off = 32; off > 0; off >>= 1) acc += __shfl_down(acc, off, 64);
    if (lane == 0) out[o] = tanhf(acc + bb[o]);
}

// ---------------------------------------------------------------------------

extern "C" void kernel_launch(void* const* d_in, const int* in_sizes, int n_in,
                              void* d_out, int out_size, void* d_ws, size_t ws_size,
                              hipStream_t stream) {
    const float* data = (const float*)d_in[0];
    const int*   edge = (const int*)d_in[1];       // [2, E] int32 (harness-converted)
    const float* W1   = (const float*)d_in[2];
    const float* b1   = (const float*)d_in[3];
    const float* W2   = (const float*)d_in[4];
    const float* b2   = (const float*)d_in[5];
    const float* W3   = (const float*)d_in[6];
    const float* b3   = (const float*)d_in[7];
    const float* Wa   = (const float*)d_in[8];
    const float* ba   = (const float*)d_in[9];
    const float* Wb   = (const float*)d_in[10];
    const float* bb   = (const float*)d_in[11];
    float* out = (float*)d_out;

    const int* src = edge;
    const int* dst = edge + NE;

    // workspace layout
    char* ws = (char*)d_ws;
    int*   cnt    = (int*)ws;                      // [NN]      memset 0
    int*   row    = cnt + NN;                      // [NN+1]
    int*   cursor = row + NN + 1;                  // [NN]
    int*   srcs   = cursor + NN;                   // [NE]
    float* dinv   = (float*)(srcs + NE);           // [NN]
    float* h1     = dinv + NN;                     // [NN*4]
    float* h2     = h1 + NN * 4;                   // [NN*2]
    float* h3     = h2 + NN * 2;                   // [NN]
    float* v      = h3 + NN;                       // [NN]
    float* y1     = v + NN;                        // [DH]

    dim3 blk(256);
    dim3 gN((NN + 255) / 256);        // 32 blocks (node-domain, thread/elem)
    dim3 gE((NE + 255) / 256);        // 2048 blocks (edge-domain)
    dim3 gW(NN / 4);                  // 2048 blocks (wave-per-node)

    hipMemsetAsync(cnt, 0, (size_t)NN * sizeof(int), stream);   // 32 KB

    k_hist <<<gE, blk, 0, stream>>>(dst, cnt);
    k_h1   <<<gN, blk, 0, stream>>>(data, W1, h1);
    k_scan <<<dim3(1), blk, 0, stream>>>(cnt, row, cursor, dinv);
    k_build<<<gE, blk, 0, stream>>>(src, dst, cursor, srcs);
    k_g4   <<<gW, blk, 0, stream>>>(row, srcs, dinv, h1, b1, W2, h2);
    k_g2   <<<gW, blk, 0, stream>>>(row, srcs, dinv, h2, b2, W3, h3);
    k_g1   <<<gW, blk, 0, stream>>>(row, srcs, dinv, h3, b3, v);
    k_mv1  <<<dim3(DH / 4), blk, 0, stream>>>(v, Wa, ba, y1);
    k_mv2  <<<dim3(NOUT / 4), blk, 0, stream>>>(y1, Wb, bb, out);
}